// Round 8
// baseline (358.300 us; speedup 1.0000x reference)
//
#include <hip/hip_runtime.h>

// GCN: 3-layer GraphConv (norm='both') + mean over nodes.
// Round 8: fp8(e4m3) activation storage halves the L3-bound gather traffic;
// agg+GEMM fused per layer through LDS (phase A: 64-row aggregation -> LDS
// bf16; phase B: MFMA vs LDS-staged bf16 hi/lo W). Layer 3 = agg + column
// partials + tiny final reduce/matvec. Zero global atomics, zero memsets.
#define N_NODES 50000
#define N_EDGES 800000
#define F 128
#define SCAN_NB 49      // ceil(50000/1024)
#define CH 64           // edge chunks
#define EPC (N_EDGES / CH)   // 12500 edges per chunk
#define HALF 25000      // node half-range (packed 16-bit hist)
#define QTR 12500       // node quarter-range (32-bit cursors)
#define BSTRIDE 17      // uint4 per LDS row (odd -> conflict-free ds_read_b128)
#define RPB 64          // rows per fused block
#define NB_L ((N_NODES + RPB - 1) / RPB)   // 782

typedef __bf16 bf16x8 __attribute__((ext_vector_type(8)));
typedef float  f32x4  __attribute__((ext_vector_type(4)));
typedef float  f32x2  __attribute__((ext_vector_type(2)));

__device__ inline unsigned short f2bf(float f) {  // RNE fp32 -> bf16 bits
    unsigned u = __float_as_uint(f);
    u += 0x7FFF + ((u >> 16) & 1);
    return (unsigned short)(u >> 16);
}
__device__ inline unsigned packbf2(float a, float b) {
    return (unsigned)f2bf(a) | ((unsigned)f2bf(b) << 16);
}

// ---- fp8 e4m3 (OCP on gfx950) helpers ----
__device__ inline void fp8x8_to_f32(uint2 u, float* f) {
    f32x2 v0 = __builtin_amdgcn_cvt_pk_f32_fp8(u.x, false);
    f32x2 v1 = __builtin_amdgcn_cvt_pk_f32_fp8(u.x, true);
    f32x2 v2 = __builtin_amdgcn_cvt_pk_f32_fp8(u.y, false);
    f32x2 v3 = __builtin_amdgcn_cvt_pk_f32_fp8(u.y, true);
    f[0] = v0.x; f[1] = v0.y; f[2] = v1.x; f[3] = v1.y;
    f[4] = v2.x; f[5] = v2.y; f[6] = v3.x; f[7] = v3.y;
}
__device__ inline unsigned f32x4_to_fp8(float a, float b, float c, float d) {
    unsigned r = __builtin_amdgcn_cvt_pk_fp8_f32(a, b, 0, false);
    r = __builtin_amdgcn_cvt_pk_fp8_f32(c, d, r, true);
    return r;
}

// ---- chunked histograms: block = (chunk, type, half), one LDS pass each ----
__global__ __launch_bounds__(1024) void hist_kernel(const int* __restrict__ src,
                                                    const int* __restrict__ dst,
                                                    int* __restrict__ Hs,
                                                    int* __restrict__ Hd) {
    __shared__ unsigned hist[HALF / 2];  // 50 KB
    int bx = blockIdx.x;
    int c = bx >> 2, t = bx & 1, h = (bx >> 1) & 1;
    const int* ids = t ? dst : src;
    int* H = t ? Hd : Hs;
    int base = h * HALF;
    for (int j = threadIdx.x; j < HALF / 2; j += 1024) hist[j] = 0;
    __syncthreads();
    int e0 = c * EPC;
    for (int e = e0 + threadIdx.x; e < e0 + EPC; e += 1024) {
        int id = ids[e] - base;
        if ((unsigned)id < (unsigned)HALF)
            atomicAdd(&hist[id >> 1], 1u << ((id & 1) * 16));
    }
    __syncthreads();
    for (int j = threadIdx.x; j < HALF / 2; j += 1024) {
        unsigned u = hist[j];
        uint2 o; o.x = u & 0xFFFFu; o.y = u >> 16;
        *(uint2*)&H[(size_t)c * N_NODES + base + 2 * j] = o;
    }
}

// ---- reduce partial hists -> degrees -> norms; fused scanA block sums ----
__global__ __launch_bounds__(1024) void reduceN_kernel(const int* __restrict__ Hs,
                                                       const int* __restrict__ Hd,
                                                       float* __restrict__ onorm,
                                                       float* __restrict__ inorm,
                                                       int* __restrict__ degd,
                                                       int* __restrict__ bsums) {
    __shared__ int wsum[16];
    int i = blockIdx.x * 1024 + threadIdx.x;
    int dd = 0;
    if (i < N_NODES) {
        int ds = 0;
        for (int c = 0; c < CH; c++) {
            ds += Hs[(size_t)c * N_NODES + i];
            dd += Hd[(size_t)c * N_NODES + i];
        }
        onorm[i] = rsqrtf(fmaxf((float)ds, 1.0f));
        inorm[i] = rsqrtf(fmaxf((float)dd, 1.0f));
        degd[i] = dd;
    }
    int v = dd;
#pragma unroll
    for (int off = 32; off; off >>= 1) v += __shfl_down(v, off);
    if ((threadIdx.x & 63) == 0) wsum[threadIdx.x >> 6] = v;
    __syncthreads();
    if (threadIdx.x == 0) {
        int s = 0;
#pragma unroll
        for (int k = 0; k < 16; k++) s += wsum[k];
        bsums[blockIdx.x] = s;
    }
}

__global__ __launch_bounds__(64) void scanB_kernel(const int* __restrict__ blockSums,
                                                   int* __restrict__ blockOffs) {
    int t = threadIdx.x;
    int v = (t < SCAN_NB) ? blockSums[t] : 0;
    int incl = v;
#pragma unroll
    for (int off = 1; off < 64; off <<= 1) {
        int u = __shfl_up(incl, off);
        if (t >= off) incl += u;
    }
    if (t < SCAN_NB) blockOffs[t] = incl - v;
}

// ---- scanC + colpref fused ----
__global__ __launch_bounds__(1024) void scanC_kernel(const int* __restrict__ deg,
                                                     const int* __restrict__ blockOffs,
                                                     int* __restrict__ rowst,
                                                     int* __restrict__ Hd) {
    __shared__ int wsum[16];
    int t = threadIdx.x, lane = t & 63, w = t >> 6;
    int i = blockIdx.x * 1024 + t;
    int v = (i < N_NODES) ? deg[i] : 0;
    int incl = v;
#pragma unroll
    for (int off = 1; off < 64; off <<= 1) {
        int u = __shfl_up(incl, off);
        if (lane >= off) incl += u;
    }
    if (lane == 63) wsum[w] = incl;
    __syncthreads();
    if (t == 0) {
        int s = 0;
#pragma unroll
        for (int k = 0; k < 16; k++) { int x = wsum[k]; wsum[k] = s; s += x; }
    }
    __syncthreads();
    incl += wsum[w] + blockOffs[blockIdx.x];
    if (i < N_NODES) {
        int s = incl - v;          // exclusive prefix
        rowst[i] = s;
        if (i == N_NODES - 1) rowst[N_NODES] = incl;
        for (int c = 0; c < CH; c++) {
            size_t o = (size_t)c * N_NODES + i;
            int x = Hd[o]; Hd[o] = s; s += x;
        }
    }
}

// ---- atomic-free scatter: block = (chunk, quarter) ----
__global__ __launch_bounds__(1024) void scatter2_kernel(const int* __restrict__ src,
                                                        const int* __restrict__ dst,
                                                        const float* __restrict__ onorm,
                                                        const int* __restrict__ P,
                                                        int2* __restrict__ epack) {
    __shared__ int cur[QTR];  // 50 KB
    int bx = blockIdx.x;
    int c = bx >> 2, q = bx & 3;
    int base = q * QTR;
    for (int j = threadIdx.x; j < QTR; j += 1024)
        cur[j] = P[(size_t)c * N_NODES + base + j];
    __syncthreads();
    int e0 = c * EPC;
    for (int e = e0 + threadIdx.x; e < e0 + EPC; e += 1024) {
        int d = dst[e] - base;
        if ((unsigned)d < (unsigned)QTR) {
            int s = src[e];
            int pos = atomicAdd(&cur[d], 1);   // LDS atomic only
            int2 p; p.x = s; p.y = __float_as_int(onorm[s]);
            epack[pos] = p;
        }
    }
}

// ---- fp32 -> fp8 bulk convert (feat -> xq) ----
__global__ __launch_bounds__(256) void cvt_kernel(const float* __restrict__ x,
                                                  uint2* __restrict__ xq, int n8) {
    int i = blockIdx.x * 256 + threadIdx.x;
    if (i < n8) {
        const float4* xv = (const float4*)x;
        float4 v0 = xv[i * 2], v1 = xv[i * 2 + 1];
        uint2 o;
        o.x = f32x4_to_fp8(v0.x, v0.y, v0.z, v0.w);
        o.y = f32x4_to_fp8(v1.x, v1.y, v1.z, v1.w);
        xq[i] = o;
    }
}

// ---- W prep: transpose W1,W2 to n-major, split bf16 hi + lo ----
__global__ __launch_bounds__(128) void wprep_kernel(const float* __restrict__ W1,
                                                    const float* __restrict__ W2,
                                                    unsigned short* __restrict__ Wt_hi,
                                                    unsigned short* __restrict__ Wt_lo) {
    int bx = blockIdx.x;            // 0..255
    int wi = bx >> 7, n = bx & 127;
    const float* W = wi ? W2 : W1;
    int k = threadIdx.x;
    float v = W[k * F + n];
    unsigned short hi = f2bf(v);
    float r = v - __uint_as_float((unsigned)hi << 16);
    size_t o = (size_t)wi * F * F + (size_t)n * F + k;
    Wt_hi[o] = hi;
    Wt_lo[o] = f2bf(r);
}

// ---- one dst row aggregation: 16 lanes/edge (uint2 fp8), 4 groups, unroll-16 ----
__device__ inline void agg_row(const uint2* __restrict__ xq,
                               const int2* __restrict__ epack,
                               int beg, int end, int g, int t, float acc[8]) {
#pragma unroll
    for (int k = 0; k < 8; k++) acc[k] = 0.0f;
    for (int e = beg; e < end; e += 16) {
        int ea = min(e + g,      end - 1);
        int eb = min(e + 4 + g,  end - 1);
        int ec = min(e + 8 + g,  end - 1);
        int ed = min(e + 12 + g, end - 1);
        int2 pa = epack[ea], pb = epack[eb], pc = epack[ec], pd = epack[ed];
        uint2 ua = xq[(size_t)pa.x * 16 + t];
        uint2 ub = xq[(size_t)pb.x * 16 + t];
        uint2 uc = xq[(size_t)pc.x * 16 + t];
        uint2 ud = xq[(size_t)pd.x * 16 + t];
        float wa = (e + g      < end) ? __int_as_float(pa.y) : 0.0f;
        float wb = (e + 4 + g  < end) ? __int_as_float(pb.y) : 0.0f;
        float wc = (e + 8 + g  < end) ? __int_as_float(pc.y) : 0.0f;
        float wd = (e + 12 + g < end) ? __int_as_float(pd.y) : 0.0f;
        float fa[8], fb[8], fc[8], fd[8];
        fp8x8_to_f32(ua, fa); fp8x8_to_f32(ub, fb);
        fp8x8_to_f32(uc, fc); fp8x8_to_f32(ud, fd);
#pragma unroll
        for (int k = 0; k < 8; k++)
            acc[k] += fa[k] * wa + fb[k] * wb + fc[k] * wc + fd[k] * wd;
    }
#pragma unroll
    for (int k = 0; k < 8; k++) {
        acc[k] += __shfl_xor(acc[k], 16, 64);
        acc[k] += __shfl_xor(acc[k], 32, 64);
    }
}

// ---- fused layer: phase A agg (64 rows -> LDS bf16), phase B MFMA, fp8 out ----
template <int RELU>
__global__ __launch_bounds__(256) void fused_layer_kernel(
        const uint2* __restrict__ xq, const int2* __restrict__ epack,
        const int* __restrict__ rowst, const float* __restrict__ inorm,
        const unsigned short* __restrict__ Wt_hi, const unsigned short* __restrict__ Wt_lo,
        const float* __restrict__ bias, unsigned char* __restrict__ y8) {
    __shared__ uint4 sA[RPB * BSTRIDE];  // 17.4 KB: 64 agg rows, bf16, stride-17
    __shared__ uint4 sB[F * BSTRIDE];    // 34.8 KB: W tile (hi then lo)
    int tid = threadIdx.x;
    int w = tid >> 6, lane = tid & 63;
    int g = lane >> 4, t = lane & 15;    // g == MFMA quad, t == r16
    int row0 = blockIdx.x * RPB;

    // phase A: wave w aggregates rows [row0+w*16, +16)
    for (int i = 0; i < 16; i++) {
        int row = row0 + w * 16 + i;
        if (row < N_NODES) {                      // wave-uniform
            int beg = __builtin_amdgcn_readfirstlane(rowst[row]);
            int end = __builtin_amdgcn_readfirstlane(rowst[row + 1]);
            float acc[8];
            agg_row(xq, epack, beg, end, g, t, acc);
            if (g == 0) {
                float inw = inorm[row];
                uint4 o;
                o.x = packbf2(acc[0] * inw, acc[1] * inw);
                o.y = packbf2(acc[2] * inw, acc[3] * inw);
                o.z = packbf2(acc[4] * inw, acc[5] * inw);
                o.w = packbf2(acc[6] * inw, acc[7] * inw);
                sA[(w * 16 + i) * BSTRIDE + t] = o;
            }
        }
    }
    __syncthreads();

    // phase B: MFMA. A-frags from sA; W staged hi then lo into sB.
    uint4 a[4];
#pragma unroll
    for (int kk = 0; kk < 4; kk++)
        a[kk] = sA[(w * 16 + t) * BSTRIDE + kk * 4 + g];

    f32x4 acc[8];
#pragma unroll
    for (int n8 = 0; n8 < 8; n8++) acc[n8] = (f32x4){0.f, 0.f, 0.f, 0.f};

    const uint4* G[2] = {(const uint4*)Wt_hi, (const uint4*)Wt_lo};
#pragma unroll
    for (int ph = 0; ph < 2; ph++) {
        if (ph) __syncthreads();
        for (int j = tid; j < F * 16; j += 256)
            sB[(j >> 4) * BSTRIDE + (j & 15)] = G[ph][j];
        __syncthreads();
#pragma unroll
        for (int kk = 0; kk < 4; kk++) {
            bf16x8 av = __builtin_bit_cast(bf16x8, a[kk]);
#pragma unroll
            for (int n8 = 0; n8 < 8; n8++) {
                bf16x8 bv = __builtin_bit_cast(bf16x8,
                    sB[(n8 * 16 + t) * BSTRIDE + kk * 4 + g]);
                acc[n8] = __builtin_amdgcn_mfma_f32_16x16x32_bf16(av, bv, acc[n8], 0, 0, 0);
            }
        }
    }

    // epilogue: +bias, relu, fp8 store. D: col = n8*16 + t, row = row0+w*16+g*4+reg
#pragma unroll
    for (int n8 = 0; n8 < 8; n8++) {
        int col = n8 * 16 + t;
        float bb = bias[col];
#pragma unroll
        for (int reg = 0; reg < 4; reg++) {
            int row = row0 + w * 16 + g * 4 + reg;
            if (row < N_NODES) {
                float v = acc[n8][reg] + bb;
                if (RELU) v = fmaxf(v, 0.0f);
                unsigned p = __builtin_amdgcn_cvt_pk_fp8_f32(v, v, 0, false);
                y8[(size_t)row * F + col] = (unsigned char)(p & 0xFF);
            }
        }
    }
}

// ---- fused layer 3: agg + per-block column partials (mean fusion) ----
__global__ __launch_bounds__(256) void fused_l3_kernel(
        const uint2* __restrict__ xq, const int2* __restrict__ epack,
        const int* __restrict__ rowst, const float* __restrict__ inorm,
        float* __restrict__ part) {
    __shared__ float sP[4][F];  // 2 KB
    int tid = threadIdx.x;
    int w = tid >> 6, lane = tid & 63;
    int g = lane >> 4, t = lane & 15;
    int row0 = blockIdx.x * RPB;
    float colacc[8];
#pragma unroll
    for (int k = 0; k < 8; k++) colacc[k] = 0.0f;

    for (int i = 0; i < 16; i++) {
        int row = row0 + w * 16 + i;
        if (row < N_NODES) {
            int beg = __builtin_amdgcn_readfirstlane(rowst[row]);
            int end = __builtin_amdgcn_readfirstlane(rowst[row + 1]);
            float acc[8];
            agg_row(xq, epack, beg, end, g, t, acc);
            if (g == 0) {
                float inw = inorm[row];
#pragma unroll
                for (int k = 0; k < 8; k++) colacc[k] += acc[k] * inw;
            }
        }
    }
    if (g == 0) {
#pragma unroll
        for (int k = 0; k < 8; k++) sP[w][t * 8 + k] = colacc[k];
    }
    __syncthreads();
    if (tid < F)
        part[(size_t)blockIdx.x * F + tid] =
            sP[0][tid] + sP[1][tid] + sP[2][tid] + sP[3][tid];
}

// ---- final: c = (1/N) * sum_b part[b], out = c @ W3 + b3 ----
__global__ __launch_bounds__(1024) void final_kernel(const float* __restrict__ part,
                                                     const float* __restrict__ W3,
                                                     const float* __restrict__ b3,
                                                     float* __restrict__ out) {
    __shared__ float sc[8][F];  // 4 KB
    int tid = threadIdx.x;
    int col = tid & 127, sl = tid >> 7;
    float acc = 0.0f;
    for (int b = sl; b < NB_L; b += 8) acc += part[(size_t)b * F + col];
    sc[sl][col] = acc;
    __syncthreads();
    if (tid < F) {
        float s = 0.0f;
#pragma unroll
        for (int k = 0; k < 8; k++) s += sc[k][tid];
        sc[0][tid] = s * (1.0f / (float)N_NODES);
    }
    __syncthreads();
    if (tid < F) {
        float o = b3[tid];
        for (int k = 0; k < F; k++) o += sc[0][k] * W3[k * F + tid];
        out[tid] = o;
    }
}

extern "C" void kernel_launch(void* const* d_in, const int* in_sizes, int n_in,
                              void* d_out, int out_size, void* d_ws, size_t ws_size,
                              hipStream_t stream) {
    const float* feat = (const float*)d_in[0];
    const float* W1   = (const float*)d_in[1];
    const float* b1   = (const float*)d_in[2];
    const float* W2   = (const float*)d_in[3];
    const float* b2   = (const float*)d_in[4];
    const float* W3   = (const float*)d_in[5];
    const float* b3   = (const float*)d_in[6];
    const int*   src  = (const int*)d_in[7];
    const int*   dst  = (const int*)d_in[8];
    float* out = (float*)d_out;

    // workspace layout (no aliasing needed; ~47 MB total)
    char* ws = (char*)d_ws;
    size_t off = 0;
    int*   Hs    = (int*)  (ws + off); off += (size_t)CH * N_NODES * 4;  // 12.8 MB
    int*   Hd    = (int*)  (ws + off); off += (size_t)CH * N_NODES * 4;  // 12.8 MB
    uint2* xq    = (uint2*)(ws + off); off += (size_t)N_NODES * F;       // 6.4 MB fp8
    uint2* hq    = (uint2*)(ws + off); off += (size_t)N_NODES * F;       // 6.4 MB fp8
    float* onorm = (float*)(ws + off); off += N_NODES * 4;
    float* inorm = (float*)(ws + off); off += N_NODES * 4;
    int*   rowst = (int*)  (ws + off); off += (N_NODES + 1) * 4;
    int*   bsums = (int*)  (ws + off); off += 64 * 4;
    int*   boffs = (int*)  (ws + off); off += 64 * 4;
    int*   degd  = (int*)  (ws + off); off += N_NODES * 4;
    unsigned short* Wt_hi = (unsigned short*)(ws + off); off += 2 * F * F * 2;
    unsigned short* Wt_lo = (unsigned short*)(ws + off); off += 2 * F * F * 2;
    float* part  = (float*)(ws + off); off += (size_t)NB_L * F * 4;      // 400 KB
    int2*  epack = (int2*) (ws + off); off += (size_t)N_EDGES * 8;       // 6.4 MB

    // CSR build — zero global atomics, all passes block-parallel
    hist_kernel<<<4 * CH, 1024, 0, stream>>>(src, dst, Hs, Hd);
    reduceN_kernel<<<SCAN_NB, 1024, 0, stream>>>(Hs, Hd, onorm, inorm, degd, bsums);
    scanB_kernel<<<1, 64, 0, stream>>>(bsums, boffs);
    scanC_kernel<<<SCAN_NB, 1024, 0, stream>>>(degd, boffs, rowst, Hd);
    scatter2_kernel<<<4 * CH, 1024, 0, stream>>>(src, dst, onorm, Hd, epack);

    // prep
    cvt_kernel<<<(N_NODES * F / 8 + 255) / 256, 256, 0, stream>>>(feat, xq, N_NODES * F / 8);
    wprep_kernel<<<256, 128, 0, stream>>>(W1, W2, Wt_hi, Wt_lo);

    // layer 1: xq -> hq
    fused_layer_kernel<1><<<NB_L, 256, 0, stream>>>(xq, epack, rowst, inorm,
                                                    Wt_hi, Wt_lo, b1, (unsigned char*)hq);
    // layer 2: hq -> xq (reuse)
    fused_layer_kernel<1><<<NB_L, 256, 0, stream>>>(hq, epack, rowst, inorm,
                                                    Wt_hi + F * F, Wt_lo + F * F, b2,
                                                    (unsigned char*)xq);
    // layer 3: agg(xq) + mean fusion -> part; then out = c @ W3 + b3
    fused_l3_kernel<<<NB_L, 256, 0, stream>>>(xq, epack, rowst, inorm, part);
    final_kernel<<<1, 1024, 0, stream>>>(part, W3, b3, out);
}

// Round 9
// 259.622 us; speedup vs baseline: 1.3801x; 1.3801x over previous
//
#include <hip/hip_runtime.h>

// GCN: 3-layer GraphConv (norm='both') + mean over nodes.
// Round 9: round-7 unfused structure (high-TLP agg + LDS-staged MFMA gemm)
// with round-8's fp8(e4m3) activation storage for the gather source.
// Agg: fp8 in -> fp32 acc -> bf16 mb out. GEMM: bf16 in (hi+lo W) -> fp8 out.
// Layer 3: agg -> per-block column partials -> 2-stage reduce -> matvec.
#define N_NODES 50000
#define N_EDGES 800000
#define F 128
#define SCAN_NB 49      // ceil(50000/1024)
#define CH 64           // edge chunks
#define EPC (N_EDGES / CH)   // 12500 edges per chunk
#define HALF 25000      // node half-range (packed 16-bit hist)
#define QTR 12500       // node quarter-range (32-bit cursors)
#define BSTRIDE 17      // uint4 per LDS row (odd -> conflict-free ds_read_b128)
#define AGG_NB (N_NODES / 4)   // 12500 agg blocks (4 waves, 1 row/wave)
#define RED_NB 256      // stage-1 partial-reduction blocks

typedef __bf16 bf16x8 __attribute__((ext_vector_type(8)));
typedef float  f32x4  __attribute__((ext_vector_type(4)));
typedef float  f32x2  __attribute__((ext_vector_type(2)));

__device__ inline unsigned short f2bf(float f) {  // RNE fp32 -> bf16 bits
    unsigned u = __float_as_uint(f);
    u += 0x7FFF + ((u >> 16) & 1);
    return (unsigned short)(u >> 16);
}
__device__ inline unsigned packbf2(float a, float b) {
    return (unsigned)f2bf(a) | ((unsigned)f2bf(b) << 16);
}

// ---- fp8 e4m3 (OCP on gfx950) helpers ----
__device__ inline void fp8x8_to_f32(uint2 u, float* f) {
    f32x2 v0 = __builtin_amdgcn_cvt_pk_f32_fp8(u.x, false);
    f32x2 v1 = __builtin_amdgcn_cvt_pk_f32_fp8(u.x, true);
    f32x2 v2 = __builtin_amdgcn_cvt_pk_f32_fp8(u.y, false);
    f32x2 v3 = __builtin_amdgcn_cvt_pk_f32_fp8(u.y, true);
    f[0] = v0.x; f[1] = v0.y; f[2] = v1.x; f[3] = v1.y;
    f[4] = v2.x; f[5] = v2.y; f[6] = v3.x; f[7] = v3.y;
}
__device__ inline unsigned f32x4_to_fp8(float a, float b, float c, float d) {
    unsigned r = __builtin_amdgcn_cvt_pk_fp8_f32(a, b, 0, false);
    r = __builtin_amdgcn_cvt_pk_fp8_f32(c, d, r, true);
    return r;
}

// ---- chunked histograms: block = (chunk, type, half), one LDS pass each ----
__global__ __launch_bounds__(1024) void hist_kernel(const int* __restrict__ src,
                                                    const int* __restrict__ dst,
                                                    int* __restrict__ Hs,
                                                    int* __restrict__ Hd) {
    __shared__ unsigned hist[HALF / 2];  // 50 KB
    int bx = blockIdx.x;
    int c = bx >> 2, t = bx & 1, h = (bx >> 1) & 1;
    const int* ids = t ? dst : src;
    int* H = t ? Hd : Hs;
    int base = h * HALF;
    for (int j = threadIdx.x; j < HALF / 2; j += 1024) hist[j] = 0;
    __syncthreads();
    int e0 = c * EPC;
    for (int e = e0 + threadIdx.x; e < e0 + EPC; e += 1024) {
        int id = ids[e] - base;
        if ((unsigned)id < (unsigned)HALF)
            atomicAdd(&hist[id >> 1], 1u << ((id & 1) * 16));
    }
    __syncthreads();
    for (int j = threadIdx.x; j < HALF / 2; j += 1024) {
        unsigned u = hist[j];
        uint2 o; o.x = u & 0xFFFFu; o.y = u >> 16;
        *(uint2*)&H[(size_t)c * N_NODES + base + 2 * j] = o;
    }
}

// ---- reduce partial hists -> degrees -> norms; fused scanA block sums ----
__global__ __launch_bounds__(1024) void reduceN_kernel(const int* __restrict__ Hs,
                                                       const int* __restrict__ Hd,
                                                       float* __restrict__ onorm,
                                                       float* __restrict__ inorm,
                                                       int* __restrict__ degd,
                                                       int* __restrict__ bsums) {
    __shared__ int wsum[16];
    int i = blockIdx.x * 1024 + threadIdx.x;
    int dd = 0;
    if (i < N_NODES) {
        int ds = 0;
        for (int c = 0; c < CH; c++) {
            ds += Hs[(size_t)c * N_NODES + i];
            dd += Hd[(size_t)c * N_NODES + i];
        }
        onorm[i] = rsqrtf(fmaxf((float)ds, 1.0f));
        inorm[i] = rsqrtf(fmaxf((float)dd, 1.0f));
        degd[i] = dd;
    }
    int v = dd;
#pragma unroll
    for (int off = 32; off; off >>= 1) v += __shfl_down(v, off);
    if ((threadIdx.x & 63) == 0) wsum[threadIdx.x >> 6] = v;
    __syncthreads();
    if (threadIdx.x == 0) {
        int s = 0;
#pragma unroll
        for (int k = 0; k < 16; k++) s += wsum[k];
        bsums[blockIdx.x] = s;
    }
}

__global__ __launch_bounds__(64) void scanB_kernel(const int* __restrict__ blockSums,
                                                   int* __restrict__ blockOffs) {
    int t = threadIdx.x;
    int v = (t < SCAN_NB) ? blockSums[t] : 0;
    int incl = v;
#pragma unroll
    for (int off = 1; off < 64; off <<= 1) {
        int u = __shfl_up(incl, off);
        if (t >= off) incl += u;
    }
    if (t < SCAN_NB) blockOffs[t] = incl - v;
}

// ---- scanC + colpref fused ----
__global__ __launch_bounds__(1024) void scanC_kernel(const int* __restrict__ deg,
                                                     const int* __restrict__ blockOffs,
                                                     int* __restrict__ rowst,
                                                     int* __restrict__ Hd) {
    __shared__ int wsum[16];
    int t = threadIdx.x, lane = t & 63, w = t >> 6;
    int i = blockIdx.x * 1024 + t;
    int v = (i < N_NODES) ? deg[i] : 0;
    int incl = v;
#pragma unroll
    for (int off = 1; off < 64; off <<= 1) {
        int u = __shfl_up(incl, off);
        if (lane >= off) incl += u;
    }
    if (lane == 63) wsum[w] = incl;
    __syncthreads();
    if (t == 0) {
        int s = 0;
#pragma unroll
        for (int k = 0; k < 16; k++) { int x = wsum[k]; wsum[k] = s; s += x; }
    }
    __syncthreads();
    incl += wsum[w] + blockOffs[blockIdx.x];
    if (i < N_NODES) {
        int s = incl - v;          // exclusive prefix
        rowst[i] = s;
        if (i == N_NODES - 1) rowst[N_NODES] = incl;
        for (int c = 0; c < CH; c++) {
            size_t o = (size_t)c * N_NODES + i;
            int x = Hd[o]; Hd[o] = s; s += x;
        }
    }
}

// ---- atomic-free scatter: block = (chunk, quarter) ----
__global__ __launch_bounds__(1024) void scatter2_kernel(const int* __restrict__ src,
                                                        const int* __restrict__ dst,
                                                        const float* __restrict__ onorm,
                                                        const int* __restrict__ P,
                                                        int2* __restrict__ epack) {
    __shared__ int cur[QTR];  // 50 KB
    int bx = blockIdx.x;
    int c = bx >> 2, q = bx & 3;
    int base = q * QTR;
    for (int j = threadIdx.x; j < QTR; j += 1024)
        cur[j] = P[(size_t)c * N_NODES + base + j];
    __syncthreads();
    int e0 = c * EPC;
    for (int e = e0 + threadIdx.x; e < e0 + EPC; e += 1024) {
        int d = dst[e] - base;
        if ((unsigned)d < (unsigned)QTR) {
            int s = src[e];
            int pos = atomicAdd(&cur[d], 1);   // LDS atomic only
            int2 p; p.x = s; p.y = __float_as_int(onorm[s]);
            epack[pos] = p;
        }
    }
}

// ---- fp32 -> fp8 bulk convert (feat -> xq) ----
__global__ __launch_bounds__(256) void cvt_kernel(const float* __restrict__ x,
                                                  uint2* __restrict__ xq, int n8) {
    int i = blockIdx.x * 256 + threadIdx.x;
    if (i < n8) {
        const float4* xv = (const float4*)x;
        float4 v0 = xv[i * 2], v1 = xv[i * 2 + 1];
        uint2 o;
        o.x = f32x4_to_fp8(v0.x, v0.y, v0.z, v0.w);
        o.y = f32x4_to_fp8(v1.x, v1.y, v1.z, v1.w);
        xq[i] = o;
    }
}

// ---- W prep: transpose W1,W2 to n-major, split bf16 hi + lo ----
__global__ __launch_bounds__(128) void wprep_kernel(const float* __restrict__ W1,
                                                    const float* __restrict__ W2,
                                                    unsigned short* __restrict__ Wt_hi,
                                                    unsigned short* __restrict__ Wt_lo) {
    int bx = blockIdx.x;            // 0..255
    int wi = bx >> 7, n = bx & 127;
    const float* W = wi ? W2 : W1;
    int k = threadIdx.x;
    float v = W[k * F + n];
    unsigned short hi = f2bf(v);
    float r = v - __uint_as_float((unsigned)hi << 16);
    size_t o = (size_t)wi * F * F + (size_t)n * F + k;
    Wt_hi[o] = hi;
    Wt_lo[o] = f2bf(r);
}

// ---- aggregation: 4 waves/block, 1 dst row/wave; 16 lanes/edge fp8 uint2 ----
// L3=0: write bf16 row to mb. L3=1: accumulate column partials -> part[block].
template <int L3>
__global__ __launch_bounds__(256) void agg_csr_kernel(const uint2* __restrict__ xq,
                                                      uint4* __restrict__ mb,
                                                      float* __restrict__ part,
                                                      const int* __restrict__ rowst,
                                                      const int2* __restrict__ epack,
                                                      const float* __restrict__ inorm) {
    __shared__ float sP[4][F];   // only used when L3
    int w = threadIdx.x >> 6;
    int lane = threadIdx.x & 63;
    int g = lane >> 4, t = lane & 15;
    int row = blockIdx.x * 4 + w;
    int beg = __builtin_amdgcn_readfirstlane(rowst[row]);
    int end = __builtin_amdgcn_readfirstlane(rowst[row + 1]);
    float acc[8];
#pragma unroll
    for (int k = 0; k < 8; k++) acc[k] = 0.0f;

    for (int e = beg; e < end; e += 16) {   // clamped, 4 gathers in flight
        int ea = min(e + g,      end - 1);
        int eb = min(e + 4 + g,  end - 1);
        int ec = min(e + 8 + g,  end - 1);
        int ed = min(e + 12 + g, end - 1);
        int2 pa = epack[ea], pb = epack[eb], pc = epack[ec], pd = epack[ed];
        uint2 ua = xq[(size_t)pa.x * 16 + t];
        uint2 ub = xq[(size_t)pb.x * 16 + t];
        uint2 uc = xq[(size_t)pc.x * 16 + t];
        uint2 ud = xq[(size_t)pd.x * 16 + t];
        float wa = (e + g      < end) ? __int_as_float(pa.y) : 0.0f;
        float wb = (e + 4 + g  < end) ? __int_as_float(pb.y) : 0.0f;
        float wc = (e + 8 + g  < end) ? __int_as_float(pc.y) : 0.0f;
        float wd = (e + 12 + g < end) ? __int_as_float(pd.y) : 0.0f;
        float fa[8], fb[8], fc[8], fd[8];
        fp8x8_to_f32(ua, fa); fp8x8_to_f32(ub, fb);
        fp8x8_to_f32(uc, fc); fp8x8_to_f32(ud, fd);
#pragma unroll
        for (int k = 0; k < 8; k++)
            acc[k] += fa[k] * wa + fb[k] * wb + fc[k] * wc + fd[k] * wd;
    }
#pragma unroll
    for (int k = 0; k < 8; k++) {
        acc[k] += __shfl_xor(acc[k], 16, 64);
        acc[k] += __shfl_xor(acc[k], 32, 64);
    }
    float inw = inorm[row];
    if (!L3) {
        if (g == 0) {
            uint4 o;
            o.x = packbf2(acc[0] * inw, acc[1] * inw);
            o.y = packbf2(acc[2] * inw, acc[3] * inw);
            o.z = packbf2(acc[4] * inw, acc[5] * inw);
            o.w = packbf2(acc[6] * inw, acc[7] * inw);
            mb[(size_t)row * 16 + t] = o;
        }
    } else {
        if (g == 0) {
#pragma unroll
            for (int k = 0; k < 8; k++) sP[w][t * 8 + k] = acc[k] * inw;
        }
        __syncthreads();
        int tid = threadIdx.x;
        if (tid < F)
            part[(size_t)blockIdx.x * F + tid] =
                sP[0][tid] + sP[1][tid] + sP[2][tid] + sP[3][tid];
    }
}

// ---- MFMA GEMM, LDS-staged B: Y8 = fp8(relu(A @ (W_hi + W_lo) + b)) ----
__global__ __launch_bounds__(256) void mfma_gemm_kernel(const unsigned short* __restrict__ A,
                                                        const unsigned short* __restrict__ Wt_hi,
                                                        const unsigned short* __restrict__ Wt_lo,
                                                        const float* __restrict__ bias,
                                                        unsigned char* __restrict__ Y8) {
    __shared__ uint4 sB[F * BSTRIDE];   // 34816 B
    int tid = threadIdx.x;
    int w = tid >> 6;
    int lane = tid & 63;
    int quad = lane >> 4, r16 = lane & 15;
    int row0 = blockIdx.x * 64 + w * 16;

    // preload A-frags (global) so loads overlap first staging
    const uint4* Arow = (const uint4*)(A + (size_t)(row0 + r16) * F);
    uint4 a[4];
#pragma unroll
    for (int kk = 0; kk < 4; kk++) a[kk] = Arow[kk * 4 + quad];

    f32x4 acc[8];
#pragma unroll
    for (int t = 0; t < 8; t++) acc[t] = (f32x4){0.f, 0.f, 0.f, 0.f};

    const uint4* G[2] = {(const uint4*)Wt_hi, (const uint4*)Wt_lo};
#pragma unroll
    for (int ph = 0; ph < 2; ph++) {
        if (ph) __syncthreads();
        for (int j = tid; j < F * 16; j += 256)
            sB[(j >> 4) * BSTRIDE + (j & 15)] = G[ph][j];
        __syncthreads();
#pragma unroll
        for (int kk = 0; kk < 4; kk++) {
            bf16x8 av = __builtin_bit_cast(bf16x8, a[kk]);
#pragma unroll
            for (int t = 0; t < 8; t++) {
                bf16x8 bv = __builtin_bit_cast(bf16x8,
                    sB[(t * 16 + r16) * BSTRIDE + kk * 4 + quad]);
                acc[t] = __builtin_amdgcn_mfma_f32_16x16x32_bf16(av, bv, acc[t], 0, 0, 0);
            }
        }
    }

#pragma unroll
    for (int t = 0; t < 8; t++) {
        int col = t * 16 + r16;
        float bb = bias[col];
#pragma unroll
        for (int reg = 0; reg < 4; reg++) {
            int row = row0 + quad * 4 + reg;
            if (row < N_NODES) {
                float v = fmaxf(acc[t][reg] + bb, 0.0f);   // relu (layers 1-2 only)
                unsigned p = __builtin_amdgcn_cvt_pk_fp8_f32(v, v, 0, false);
                Y8[(size_t)row * F + col] = (unsigned char)(p & 0xFF);
            }
        }
    }
}

// ---- stage-1 partial reduce: part[12500][F] -> part2[RED_NB][F] ----
__global__ __launch_bounds__(128) void redpart_kernel(const float* __restrict__ part,
                                                      float* __restrict__ part2) {
    int tid = threadIdx.x;
    float acc = 0.0f;
    for (int r = blockIdx.x; r < AGG_NB; r += RED_NB)
        acc += part[(size_t)r * F + tid];
    part2[(size_t)blockIdx.x * F + tid] = acc;
}

// ---- final: c = (1/N) * sum_b part2[b], out = c @ W3 + b3 ----
__global__ __launch_bounds__(1024) void final_kernel(const float* __restrict__ part2,
                                                     const float* __restrict__ W3,
                                                     const float* __restrict__ b3,
                                                     float* __restrict__ out) {
    __shared__ float sc[8][F];  // 4 KB
    int tid = threadIdx.x;
    int col = tid & 127, sl = tid >> 7;
    float acc = 0.0f;
    for (int b = sl; b < RED_NB; b += 8) acc += part2[(size_t)b * F + col];
    sc[sl][col] = acc;
    __syncthreads();
    if (tid < F) {
        float s = 0.0f;
#pragma unroll
        for (int k = 0; k < 8; k++) s += sc[k][tid];
        sc[0][tid] = s * (1.0f / (float)N_NODES);
    }
    __syncthreads();
    if (tid < F) {
        float o = b3[tid];
        for (int k = 0; k < F; k++) o += sc[0][k] * W3[k * F + tid];
        out[tid] = o;
    }
}

extern "C" void kernel_launch(void* const* d_in, const int* in_sizes, int n_in,
                              void* d_out, int out_size, void* d_ws, size_t ws_size,
                              hipStream_t stream) {
    const float* feat = (const float*)d_in[0];
    const float* W1   = (const float*)d_in[1];
    const float* b1   = (const float*)d_in[2];
    const float* W2   = (const float*)d_in[3];
    const float* b2   = (const float*)d_in[4];
    const float* W3   = (const float*)d_in[5];
    const float* b3   = (const float*)d_in[6];
    const int*   src  = (const int*)d_in[7];
    const int*   dst  = (const int*)d_in[8];
    float* out = (float*)d_out;

    // workspace layout. Hs/Hd (25.6 MB) are dead after scatter2:
    //   mb (12.8 MB bf16) aliases Hs; part (6.4 MB) aliases Hd.
    char* ws = (char*)d_ws;
    size_t off = 0;
    int*   Hs    = (int*)  (ws + off);
    uint4* mb    = (uint4*)(ws + off); off += (size_t)CH * N_NODES * 4;  // 12.8 MB
    int*   Hd    = (int*)  (ws + off);
    float* part  = (float*)(ws + off); off += (size_t)CH * N_NODES * 4;  // 12.8 MB
    uint2* xq    = (uint2*)(ws + off); off += (size_t)N_NODES * F;       // 6.4 MB fp8
    uint2* hq    = (uint2*)(ws + off); off += (size_t)N_NODES * F;       // 6.4 MB fp8
    float* onorm = (float*)(ws + off); off += N_NODES * 4;
    float* inorm = (float*)(ws + off); off += N_NODES * 4;
    int*   rowst = (int*)  (ws + off); off += (N_NODES + 1) * 4;
    int*   bsums = (int*)  (ws + off); off += 64 * 4;
    int*   boffs = (int*)  (ws + off); off += 64 * 4;
    int*   degd  = (int*)  (ws + off); off += N_NODES * 4;
    unsigned short* Wt_hi = (unsigned short*)(ws + off); off += 2 * F * F * 2;
    unsigned short* Wt_lo = (unsigned short*)(ws + off); off += 2 * F * F * 2;
    float* part2 = (float*)(ws + off); off += (size_t)RED_NB * F * 4;    // 131 KB
    int2*  epack = (int2*) (ws + off); off += (size_t)N_EDGES * 8;       // 6.4 MB

    const int GB = (N_NODES + 63) / 64;          // 782 (store row-guarded)

    // CSR build — zero global atomics, all passes block-parallel
    hist_kernel<<<4 * CH, 1024, 0, stream>>>(src, dst, Hs, Hd);
    reduceN_kernel<<<SCAN_NB, 1024, 0, stream>>>(Hs, Hd, onorm, inorm, degd, bsums);
    scanB_kernel<<<1, 64, 0, stream>>>(bsums, boffs);
    scanC_kernel<<<SCAN_NB, 1024, 0, stream>>>(degd, boffs, rowst, Hd);
    scatter2_kernel<<<4 * CH, 1024, 0, stream>>>(src, dst, onorm, Hd, epack);

    // prep
    cvt_kernel<<<(N_NODES * F / 8 + 255) / 256, 256, 0, stream>>>(feat, xq, N_NODES * F / 8);
    wprep_kernel<<<256, 128, 0, stream>>>(W1, W2, Wt_hi, Wt_lo);

    // layer 1: agg(xq) -> mb (bf16), gemm -> hq (fp8)
    agg_csr_kernel<0><<<AGG_NB, 256, 0, stream>>>(xq, mb, part, rowst, epack, inorm);
    mfma_gemm_kernel<<<GB, 256, 0, stream>>>((const unsigned short*)mb, Wt_hi, Wt_lo, b1,
                                             (unsigned char*)hq);
    // layer 2: agg(hq) -> mb, gemm -> xq (reuse)
    agg_csr_kernel<0><<<AGG_NB, 256, 0, stream>>>(hq, mb, part, rowst, epack, inorm);
    mfma_gemm_kernel<<<GB, 256, 0, stream>>>((const unsigned short*)mb, Wt_hi + F * F,
                                             Wt_lo + F * F, b2, (unsigned char*)xq);
    // layer 3: agg(xq) -> column partials; reduce; out = c @ W3 + b3
    agg_csr_kernel<1><<<AGG_NB, 256, 0, stream>>>(xq, mb, part, rowst, epack, inorm);
    redpart_kernel<<<RED_NB, 128, 0, stream>>>(part, part2);
    final_kernel<<<1, 1024, 0, stream>>>(part2, W3, b3, out);
}

// Round 10
// 245.872 us; speedup vs baseline: 1.4573x; 1.0559x over previous
//
#include <hip/hip_runtime.h>

// GCN: 3-layer GraphConv (norm='both') + mean over nodes.
// Round 10: layer-3 aggregation deleted via edge-collapse:
//   mean_i h3 = [(1/N) sum_s t[s] * xq3[s,:]] @ W3 + b3,
//   t[s] = sum_{e: src=s} inorm[dst(e)]  (graph-only, built once).
// onorm prescaled into fp8 activations (cvt / gemm epilogue), so the edge
// record is a bare int src. ushort partial hists halve build traffic.
// Zero global atomics, zero memsets.
#define N_NODES 50000
#define N_EDGES 800000
#define F 128
#define SCAN_NB 49      // ceil(50000/1024)
#define CH 64           // edge chunks
#define EPC (N_EDGES / CH)   // 12500 edges per chunk
#define HALF 25000      // node half-range (packed 16-bit hist)
#define QTR 12500       // node quarter-range (cursors / float bins)
#define BSTRIDE 17      // uint4 per LDS row (odd -> conflict-free ds_read_b128)
#define AGG_NB (N_NODES / 4)   // 12500 agg blocks (4 waves, 1 row/wave)
#define RED_NB 256      // column-partial blocks

typedef __bf16 bf16x8 __attribute__((ext_vector_type(8)));
typedef float  f32x4  __attribute__((ext_vector_type(4)));
typedef float  f32x2  __attribute__((ext_vector_type(2)));

__device__ inline unsigned short f2bf(float f) {  // RNE fp32 -> bf16 bits
    unsigned u = __float_as_uint(f);
    u += 0x7FFF + ((u >> 16) & 1);
    return (unsigned short)(u >> 16);
}
__device__ inline unsigned packbf2(float a, float b) {
    return (unsigned)f2bf(a) | ((unsigned)f2bf(b) << 16);
}

// ---- fp8 e4m3 (OCP on gfx950) helpers ----
__device__ inline void fp8x8_to_f32(uint2 u, float* f) {
    f32x2 v0 = __builtin_amdgcn_cvt_pk_f32_fp8(u.x, false);
    f32x2 v1 = __builtin_amdgcn_cvt_pk_f32_fp8(u.x, true);
    f32x2 v2 = __builtin_amdgcn_cvt_pk_f32_fp8(u.y, false);
    f32x2 v3 = __builtin_amdgcn_cvt_pk_f32_fp8(u.y, true);
    f[0] = v0.x; f[1] = v0.y; f[2] = v1.x; f[3] = v1.y;
    f[4] = v2.x; f[5] = v2.y; f[6] = v3.x; f[7] = v3.y;
}
__device__ inline unsigned f32x4_to_fp8(float a, float b, float c, float d) {
    unsigned r = __builtin_amdgcn_cvt_pk_fp8_f32(a, b, 0, false);
    r = __builtin_amdgcn_cvt_pk_fp8_f32(c, d, r, true);
    return r;
}

// ---- chunked histograms -> ushort partials: block = (chunk, type, half) ----
__global__ __launch_bounds__(1024) void hist_kernel(const int* __restrict__ src,
                                                    const int* __restrict__ dst,
                                                    unsigned short* __restrict__ Hs16,
                                                    unsigned short* __restrict__ Hd16) {
    __shared__ unsigned hist[HALF / 2];  // 50 KB
    int bx = blockIdx.x;
    int c = bx >> 2, t = bx & 1, h = (bx >> 1) & 1;
    const int* ids = t ? dst : src;
    unsigned short* H = t ? Hd16 : Hs16;
    int base = h * HALF;
    for (int j = threadIdx.x; j < HALF / 2; j += 1024) hist[j] = 0;
    __syncthreads();
    int e0 = c * EPC;
    for (int e = e0 + threadIdx.x; e < e0 + EPC; e += 1024) {
        int id = ids[e] - base;
        if ((unsigned)id < (unsigned)HALF)
            atomicAdd(&hist[id >> 1], 1u << ((id & 1) * 16));
    }
    __syncthreads();
    for (int j = threadIdx.x; j < HALF / 2; j += 1024)
        *(unsigned*)&H[(size_t)c * N_NODES + base + 2 * j] = hist[j];
}

// ---- reduce partial hists -> norms; fused scanA block sums ----
__global__ __launch_bounds__(1024) void reduceN_kernel(const unsigned short* __restrict__ Hs16,
                                                       const unsigned short* __restrict__ Hd16,
                                                       float* __restrict__ onorm,
                                                       float* __restrict__ inorm,
                                                       int* __restrict__ degd,
                                                       int* __restrict__ bsums) {
    __shared__ int wsum[16];
    int i = blockIdx.x * 1024 + threadIdx.x;
    int dd = 0;
    if (i < N_NODES) {
        int ds = 0;
        for (int c = 0; c < CH; c++) {
            ds += Hs16[(size_t)c * N_NODES + i];
            dd += Hd16[(size_t)c * N_NODES + i];
        }
        onorm[i] = rsqrtf(fmaxf((float)ds, 1.0f));
        inorm[i] = rsqrtf(fmaxf((float)dd, 1.0f));
        degd[i] = dd;
    }
    int v = dd;
#pragma unroll
    for (int off = 32; off; off >>= 1) v += __shfl_down(v, off);
    if ((threadIdx.x & 63) == 0) wsum[threadIdx.x >> 6] = v;
    __syncthreads();
    if (threadIdx.x == 0) {
        int s = 0;
#pragma unroll
        for (int k = 0; k < 16; k++) s += wsum[k];
        bsums[blockIdx.x] = s;
    }
}

__global__ __launch_bounds__(64) void scanB_kernel(const int* __restrict__ blockSums,
                                                   int* __restrict__ blockOffs) {
    int t = threadIdx.x;
    int v = (t < SCAN_NB) ? blockSums[t] : 0;
    int incl = v;
#pragma unroll
    for (int off = 1; off < 64; off <<= 1) {
        int u = __shfl_up(incl, off);
        if (t >= off) incl += u;
    }
    if (t < SCAN_NB) blockOffs[t] = incl - v;
}

// ---- t[s] = sum_{e:src=s} inorm[dst(e)]: chunked LDS float accumulation ----
__global__ __launch_bounds__(1024) void tq_kernel(const int* __restrict__ src,
                                                  const int* __restrict__ dst,
                                                  const float* __restrict__ inorm,
                                                  float* __restrict__ Tq) {
    __shared__ float a[QTR];  // 50 KB
    int bx = blockIdx.x;
    int c = bx >> 2, q = bx & 3;
    int base = q * QTR;
    for (int j = threadIdx.x; j < QTR; j += 1024) a[j] = 0.0f;
    __syncthreads();
    int e0 = c * EPC;
    for (int e = e0 + threadIdx.x; e < e0 + EPC; e += 1024) {
        int s = src[e] - base;
        if ((unsigned)s < (unsigned)QTR)
            atomicAdd(&a[s], inorm[dst[e]]);   // LDS float atomic (ds_add_f32)
    }
    __syncthreads();
    for (int j = threadIdx.x; j < QTR; j += 1024)
        Tq[(size_t)c * N_NODES + base + j] = a[j];
}

// ---- scanC: rowst + colpref (Hd16 -> P) + q reduction, one node/thread ----
__global__ __launch_bounds__(1024) void scanC_kernel(const int* __restrict__ deg,
                                                     const int* __restrict__ blockOffs,
                                                     int* __restrict__ rowst,
                                                     const unsigned short* __restrict__ Hd16,
                                                     int* __restrict__ P,
                                                     const float* __restrict__ Tq,
                                                     float* __restrict__ qt) {
    __shared__ int wsum[16];
    int t = threadIdx.x, lane = t & 63, w = t >> 6;
    int i = blockIdx.x * 1024 + t;
    int v = (i < N_NODES) ? deg[i] : 0;
    int incl = v;
#pragma unroll
    for (int off = 1; off < 64; off <<= 1) {
        int u = __shfl_up(incl, off);
        if (lane >= off) incl += u;
    }
    if (lane == 63) wsum[w] = incl;
    __syncthreads();
    if (t == 0) {
        int s = 0;
#pragma unroll
        for (int k = 0; k < 16; k++) { int x = wsum[k]; wsum[k] = s; s += x; }
    }
    __syncthreads();
    incl += wsum[w] + blockOffs[blockIdx.x];
    if (i < N_NODES) {
        int s = incl - v;          // exclusive prefix
        rowst[i] = s;
        if (i == N_NODES - 1) rowst[N_NODES] = incl;
        float tsum = 0.0f;
        for (int c = 0; c < CH; c++) {
            size_t o = (size_t)c * N_NODES + i;
            P[o] = s; s += Hd16[o];
            tsum += Tq[o];
        }
        qt[i] = tsum;              // xq3 is onorm-prescaled, so q == t
    }
}

// ---- atomic-free scatter: block = (chunk, quarter); writes bare src int ----
__global__ __launch_bounds__(1024) void scatter2_kernel(const int* __restrict__ src,
                                                        const int* __restrict__ dst,
                                                        const int* __restrict__ P,
                                                        int* __restrict__ esrc) {
    __shared__ int cur[QTR];  // 50 KB
    int bx = blockIdx.x;
    int c = bx >> 2, q = bx & 3;
    int base = q * QTR;
    for (int j = threadIdx.x; j < QTR; j += 1024)
        cur[j] = P[(size_t)c * N_NODES + base + j];
    __syncthreads();
    int e0 = c * EPC;
    for (int e = e0 + threadIdx.x; e < e0 + EPC; e += 1024) {
        int d = dst[e] - base;
        if ((unsigned)d < (unsigned)QTR) {
            int pos = atomicAdd(&cur[d], 1);   // LDS atomic only
            esrc[pos] = src[e];
        }
    }
}

// ---- fp32 -> fp8, onorm-prescaled (feat*onorm[row] -> xq) ----
__global__ __launch_bounds__(256) void cvt_kernel(const float* __restrict__ x,
                                                  const float* __restrict__ onorm,
                                                  uint2* __restrict__ xq, int n8) {
    int i = blockIdx.x * 256 + threadIdx.x;
    if (i < n8) {
        float w = onorm[i >> 4];   // 16 uint2 per 128-col row
        const float4* xv = (const float4*)x;
        float4 v0 = xv[i * 2], v1 = xv[i * 2 + 1];
        uint2 o;
        o.x = f32x4_to_fp8(v0.x * w, v0.y * w, v0.z * w, v0.w * w);
        o.y = f32x4_to_fp8(v1.x * w, v1.y * w, v1.z * w, v1.w * w);
        xq[i] = o;
    }
}

// ---- W prep: transpose W1,W2 to n-major, split bf16 hi + lo ----
__global__ __launch_bounds__(128) void wprep_kernel(const float* __restrict__ W1,
                                                    const float* __restrict__ W2,
                                                    unsigned short* __restrict__ Wt_hi,
                                                    unsigned short* __restrict__ Wt_lo) {
    int bx = blockIdx.x;            // 0..255
    int wi = bx >> 7, n = bx & 127;
    const float* W = wi ? W2 : W1;
    int k = threadIdx.x;
    float v = W[k * F + n];
    unsigned short hi = f2bf(v);
    float r = v - __uint_as_float((unsigned)hi << 16);
    size_t o = (size_t)wi * F * F + (size_t)n * F + k;
    Wt_hi[o] = hi;
    Wt_lo[o] = f2bf(r);
}

// ---- aggregation: 4 waves/block, 1 dst row/wave; 16 lanes/edge fp8 uint2 ----
// sources already onorm-prescaled; mask handles the tail.
__global__ __launch_bounds__(256) void agg_csr_kernel(const uint2* __restrict__ xq,
                                                      uint4* __restrict__ mb,
                                                      const int* __restrict__ rowst,
                                                      const int* __restrict__ esrc,
                                                      const float* __restrict__ inorm) {
    int w = threadIdx.x >> 6;
    int lane = threadIdx.x & 63;
    int g = lane >> 4, t = lane & 15;
    int row = blockIdx.x * 4 + w;
    int beg = __builtin_amdgcn_readfirstlane(rowst[row]);
    int end = __builtin_amdgcn_readfirstlane(rowst[row + 1]);
    float acc[8];
#pragma unroll
    for (int k = 0; k < 8; k++) acc[k] = 0.0f;

    for (int e = beg; e < end; e += 16) {   // clamped, 4 gathers in flight
        int ea = min(e + g,      end - 1);
        int eb = min(e + 4 + g,  end - 1);
        int ec = min(e + 8 + g,  end - 1);
        int ed = min(e + 12 + g, end - 1);
        int sa = esrc[ea], sb = esrc[eb], sc = esrc[ec], sd = esrc[ed];
        uint2 ua = xq[(size_t)sa * 16 + t];
        uint2 ub = xq[(size_t)sb * 16 + t];
        uint2 uc = xq[(size_t)sc * 16 + t];
        uint2 ud = xq[(size_t)sd * 16 + t];
        float wa = (e + g      < end) ? 1.0f : 0.0f;
        float wb = (e + 4 + g  < end) ? 1.0f : 0.0f;
        float wc = (e + 8 + g  < end) ? 1.0f : 0.0f;
        float wd = (e + 12 + g < end) ? 1.0f : 0.0f;
        float fa[8], fb[8], fc[8], fd[8];
        fp8x8_to_f32(ua, fa); fp8x8_to_f32(ub, fb);
        fp8x8_to_f32(uc, fc); fp8x8_to_f32(ud, fd);
#pragma unroll
        for (int k = 0; k < 8; k++)
            acc[k] += fa[k] * wa + fb[k] * wb + fc[k] * wc + fd[k] * wd;
    }
#pragma unroll
    for (int k = 0; k < 8; k++) {
        acc[k] += __shfl_xor(acc[k], 16, 64);
        acc[k] += __shfl_xor(acc[k], 32, 64);
    }
    if (g == 0) {
        float inw = inorm[row];
        uint4 o;
        o.x = packbf2(acc[0] * inw, acc[1] * inw);
        o.y = packbf2(acc[2] * inw, acc[3] * inw);
        o.z = packbf2(acc[4] * inw, acc[5] * inw);
        o.w = packbf2(acc[6] * inw, acc[7] * inw);
        mb[(size_t)row * 16 + t] = o;
    }
}

// ---- MFMA GEMM, LDS-staged B: Y8 = fp8(onorm[row] * relu(A@(Whi+Wlo)+b)) ----
__global__ __launch_bounds__(256) void mfma_gemm_kernel(const unsigned short* __restrict__ A,
                                                        const unsigned short* __restrict__ Wt_hi,
                                                        const unsigned short* __restrict__ Wt_lo,
                                                        const float* __restrict__ bias,
                                                        const float* __restrict__ onorm,
                                                        unsigned char* __restrict__ Y8) {
    __shared__ uint4 sB[F * BSTRIDE];   // 34816 B
    int tid = threadIdx.x;
    int w = tid >> 6;
    int lane = tid & 63;
    int quad = lane >> 4, r16 = lane & 15;
    int row0 = blockIdx.x * 64 + w * 16;

    // preload A-frags (global) so loads overlap first staging
    const uint4* Arow = (const uint4*)(A + (size_t)(row0 + r16) * F);
    uint4 a[4];
#pragma unroll
    for (int kk = 0; kk < 4; kk++) a[kk] = Arow[kk * 4 + quad];

    f32x4 acc[8];
#pragma unroll
    for (int t = 0; t < 8; t++) acc[t] = (f32x4){0.f, 0.f, 0.f, 0.f};

    const uint4* G[2] = {(const uint4*)Wt_hi, (const uint4*)Wt_lo};
#pragma unroll
    for (int ph = 0; ph < 2; ph++) {
        if (ph) __syncthreads();
        for (int j = tid; j < F * 16; j += 256)
            sB[(j >> 4) * BSTRIDE + (j & 15)] = G[ph][j];
        __syncthreads();
#pragma unroll
        for (int kk = 0; kk < 4; kk++) {
            bf16x8 av = __builtin_bit_cast(bf16x8, a[kk]);
#pragma unroll
            for (int t = 0; t < 8; t++) {
                bf16x8 bv = __builtin_bit_cast(bf16x8,
                    sB[(t * 16 + r16) * BSTRIDE + kk * 4 + quad]);
                acc[t] = __builtin_amdgcn_mfma_f32_16x16x32_bf16(av, bv, acc[t], 0, 0, 0);
            }
        }
    }

    float onw[4];
#pragma unroll
    for (int reg = 0; reg < 4; reg++) {
        int row = row0 + quad * 4 + reg;
        onw[reg] = (row < N_NODES) ? onorm[row] : 0.0f;
    }
#pragma unroll
    for (int t = 0; t < 8; t++) {
        int col = t * 16 + r16;
        float bb = bias[col];
#pragma unroll
        for (int reg = 0; reg < 4; reg++) {
            int row = row0 + quad * 4 + reg;
            if (row < N_NODES) {
                float v = fmaxf(acc[t][reg] + bb, 0.0f) * onw[reg];
                unsigned p = __builtin_amdgcn_cvt_pk_fp8_f32(v, v, 0, false);
                Y8[(size_t)row * F + col] = (unsigned char)(p & 0xFF);
            }
        }
    }
}

// ---- layer-3 collapse: part2[b][j] = sum_rows qt[r] * fp8dec(xq3[r][j]) ----
__global__ __launch_bounds__(256) void colsum_kernel(const unsigned short* __restrict__ x8,
                                                     const float* __restrict__ qt,
                                                     float* __restrict__ part2) {
    __shared__ float sP[4][F];  // 2 KB
    int tid = threadIdx.x;
    int w = tid >> 6, lane = tid & 63;
    float a0 = 0.0f, a1 = 0.0f;
    for (int r = blockIdx.x * 4 + w; r < N_NODES; r += RED_NB * 4) {
        float q = qt[r];
        unsigned us = x8[(size_t)r * 64 + lane];   // 2 fp8 bytes
        f32x2 v = __builtin_amdgcn_cvt_pk_f32_fp8(us, false);
        a0 += v.x * q; a1 += v.y * q;
    }
    sP[w][lane * 2] = a0; sP[w][lane * 2 + 1] = a1;
    __syncthreads();
    if (tid < F)
        part2[(size_t)blockIdx.x * F + tid] =
            sP[0][tid] + sP[1][tid] + sP[2][tid] + sP[3][tid];
}

// ---- final: c = (1/N) * sum_b part2[b], out = c @ W3 + b3 ----
__global__ __launch_bounds__(1024) void final_kernel(const float* __restrict__ part2,
                                                     const float* __restrict__ W3,
                                                     const float* __restrict__ b3,
                                                     float* __restrict__ out) {
    __shared__ float sc[8][F];  // 4 KB
    int tid = threadIdx.x;
    int col = tid & 127, sl = tid >> 7;
    float acc = 0.0f;
    for (int b = sl; b < RED_NB; b += 8) acc += part2[(size_t)b * F + col];
    sc[sl][col] = acc;
    __syncthreads();
    if (tid < F) {
        float s = 0.0f;
#pragma unroll
        for (int k = 0; k < 8; k++) s += sc[k][tid];
        sc[0][tid] = s * (1.0f / (float)N_NODES);
    }
    __syncthreads();
    if (tid < F) {
        float o = b3[tid];
        for (int k = 0; k < F; k++) o += sc[0][k] * W3[k * F + tid];
        out[tid] = o;
    }
}

extern "C" void kernel_launch(void* const* d_in, const int* in_sizes, int n_in,
                              void* d_out, int out_size, void* d_ws, size_t ws_size,
                              hipStream_t stream) {
    const float* feat = (const float*)d_in[0];
    const float* W1   = (const float*)d_in[1];
    const float* b1   = (const float*)d_in[2];
    const float* W2   = (const float*)d_in[3];
    const float* b2   = (const float*)d_in[4];
    const float* W3   = (const float*)d_in[5];
    const float* b3   = (const float*)d_in[6];
    const int*   src  = (const int*)d_in[7];
    const int*   dst  = (const int*)d_in[8];
    float* out = (float*)d_out;

    // workspace layout (~68 MB, no aliasing; 16B-aligned blocks first)
    char* ws = (char*)d_ws;
    size_t off = 0;
    uint4* mb    = (uint4*)(ws + off); off += (size_t)N_NODES * F * 2;       // 12.8 MB bf16
    float* Tq    = (float*)(ws + off); off += (size_t)CH * N_NODES * 4;      // 12.8 MB
    int*   P     = (int*)  (ws + off); off += (size_t)CH * N_NODES * 4;      // 12.8 MB
    unsigned short* Hs16 = (unsigned short*)(ws + off); off += (size_t)CH * N_NODES * 2;  // 6.4 MB
    unsigned short* Hd16 = (unsigned short*)(ws + off); off += (size_t)CH * N_NODES * 2;  // 6.4 MB
    uint2* xq    = (uint2*)(ws + off); off += (size_t)N_NODES * F;           // 6.4 MB fp8
    uint2* hq    = (uint2*)(ws + off); off += (size_t)N_NODES * F;           // 6.4 MB fp8
    unsigned short* Wt_hi = (unsigned short*)(ws + off); off += 2 * F * F * 2;
    unsigned short* Wt_lo = (unsigned short*)(ws + off); off += 2 * F * F * 2;
    float* part2 = (float*)(ws + off); off += (size_t)RED_NB * F * 4;        // 131 KB
    int*   esrc  = (int*)  (ws + off); off += (size_t)N_EDGES * 4;           // 3.2 MB
    float* onorm = (float*)(ws + off); off += N_NODES * 4;
    float* inorm = (float*)(ws + off); off += N_NODES * 4;
    float* qt    = (float*)(ws + off); off += N_NODES * 4;
    int*   degd  = (int*)  (ws + off); off += N_NODES * 4;
    int*   rowst = (int*)  (ws + off); off += (N_NODES + 1) * 4;
    int*   bsums = (int*)  (ws + off); off += 64 * 4;
    int*   boffs = (int*)  (ws + off); off += 64 * 4;

    const int GB = (N_NODES + 63) / 64;          // 782 (store row-guarded)

    // CSR build + t[s] — zero global atomics, zero memsets
    hist_kernel<<<4 * CH, 1024, 0, stream>>>(src, dst, Hs16, Hd16);
    reduceN_kernel<<<SCAN_NB, 1024, 0, stream>>>(Hs16, Hd16, onorm, inorm, degd, bsums);
    scanB_kernel<<<1, 64, 0, stream>>>(bsums, boffs);
    tq_kernel<<<4 * CH, 1024, 0, stream>>>(src, dst, inorm, Tq);
    scanC_kernel<<<SCAN_NB, 1024, 0, stream>>>(degd, boffs, rowst, Hd16, P, Tq, qt);
    scatter2_kernel<<<4 * CH, 1024, 0, stream>>>(src, dst, P, esrc);

    // prep (cvt needs onorm -> after reduceN)
    cvt_kernel<<<(N_NODES * F / 8 + 255) / 256, 256, 0, stream>>>(feat, onorm, xq, N_NODES * F / 8);
    wprep_kernel<<<256, 128, 0, stream>>>(W1, W2, Wt_hi, Wt_lo);

    // layer 1: agg(xq) -> mb (bf16), gemm -> hq (fp8, onorm-prescaled)
    agg_csr_kernel<<<AGG_NB, 256, 0, stream>>>(xq, mb, rowst, esrc, inorm);
    mfma_gemm_kernel<<<GB, 256, 0, stream>>>((const unsigned short*)mb, Wt_hi, Wt_lo, b1,
                                             onorm, (unsigned char*)hq);
    // layer 2: agg(hq) -> mb, gemm -> xq (reused as xq3)
    agg_csr_kernel<<<AGG_NB, 256, 0, stream>>>(hq, mb, rowst, esrc, inorm);
    mfma_gemm_kernel<<<GB, 256, 0, stream>>>((const unsigned short*)mb, Wt_hi + F * F,
                                             Wt_lo + F * F, b2, onorm, (unsigned char*)xq);
    // layer 3 collapsed: c = (1/N) sum_s t[s]*xq3[s,:]; out = c @ W3 + b3
    colsum_kernel<<<RED_NB, 256, 0, stream>>>((const unsigned short*)xq, qt, part2);
    final_kernel<<<1, 1024, 0, stream>>>(part2, W3, b3, out);
}